// Round 21
// baseline (129.884 us; speedup 1.0000x reference)
//
#include <hip/hip_runtime.h>

// Problem constants: B=32, C=768, H=W=24 -> HW=576
#define B_  32
#define C_  768
#define HW_ 576

#define NCQ 18               // HW_/32 k-chunks (qk)
#define NCP 24               // C_/32 k-chunks (pv)

typedef _Float16 half8 __attribute__((ext_vector_type(8)));
typedef _Float16 half4 __attribute__((ext_vector_type(4)));
typedef float    f32x4 __attribute__((ext_vector_type(4)));

__device__ __forceinline__ void g2l16(const void* g, void* l) {
    __builtin_amdgcn_global_load_lds(
        (const __attribute__((address_space(1))) unsigned int*)g,
        (__attribute__((address_space(3))) unsigned int*)l, 16, 0, 0);
}

#define VM(N) asm volatile("s_waitcnt vmcnt(" #N ")" ::: "memory")

// attnE holds exp(S - mx_half) in fp16, LINEARIZED chunk-major:
//   elem index = ((bz*6 + strip)*24 + chunk)*4096 + row_in_strip*32 + col_in_chunk
// pv rescales by exp(mx_half - m_row)*gamma/s_row per (row, 96-col half).

// ---------------------------------------------------------------------------
// prep6: SINGLE DELTA vs round-20: the qk-branch streams f1/f2 through the
// g2l HARDWARE async queue (compiler cannot re-serialize it; rounds 19/20
// showed hipcc pins flat loads at ~2 outstanding -> 2.8 TB/s). Per-wave
// zero-barrier pipeline: ring-3 x 8KB slots, 2 g2l/chunk/wave, counted
// vmcnt(4), read OWN staged 32B, convert, scatter half4 (prep3's proven
// formula -> output bytes identical). vt branch unchanged (round-20 exact).
// ---------------------------------------------------------------------------
__global__ __launch_bounds__(256) void prep6(const float* __restrict__ f1,
                                             const float* __restrict__ f2,
                                             char* __restrict__ q16,
                                             char* __restrict__ kv16,
                                             char* __restrict__ vt,
                                             int b0, int cur, int nst) {
    __shared__ __align__(16) char Lb[25984];       // qk: 3x8KB ring; vt: 25.7KB
    const int bid = blockIdx.x;
    if (bid < nst) {
        // u in [0,48): sel = u&1 (0:f1->q16, 1:f2->kv16), rg = (u>>1)&3, ti = u>>3
        const int bz = bid % cur, u = bid / cur;
        const int sel = u & 1, rg = (u >> 1) & 3, ti = u >> 3;
        const float* s = (sel ? f2 : f1) + ((size_t)(b0 + bz) * C_ + ti * 128 + rg * 32) * HW_;
        char* d = (sel ? kv16 : q16) + ((size_t)(bz * 6 + ti)) * (NCQ * 8192);
        const int t = threadIdx.x, lane = t & 63, w = t >> 6;
        const char* gsrc = (const char*)s + w * 1024 + lane * 16;
        const int lbase = w * 1024 + lane * 16;

        // scatter one f32x4 (global float index g, 4 consecutive floats,
        // never crossing a row: 576%4==0 and g%4==0)
        auto scat = [&](f32x4 v, int g) {
            int row_l = g / 576;
            int col   = g - row_l * 576;
            int row   = rg * 32 + row_l;
            int k0    = col >> 5, kk = col & 31;
            int x     = (kk >> 3) ^ ((row >> 1) & 3);
            half4 h;
            #pragma unroll
            for (int e = 0; e < 4; ++e) h[e] = (_Float16)v[e];
            *(half4*)(d + (size_t)k0 * 8192 + row * 64 + x * 16 + (kk & 7) * 2) = h;
        };

#define PST(c) do {                                                     \
        g2l16(gsrc + (size_t)(c) * 8192,        Lb + ((c) % 3) * 8192 + w * 1024); \
        g2l16(gsrc + (size_t)(c) * 8192 + 4096, Lb + ((c) % 3) * 8192 + 4096 + w * 1024); \
    } while (0)
#define PRC(c) do {                                                     \
        f32x4 v0 = *(const f32x4*)(Lb + ((c) % 3) * 8192 + lbase);      \
        f32x4 v1 = *(const f32x4*)(Lb + ((c) % 3) * 8192 + 4096 + lbase); \
        int g0 = (c) * 2048 + w * 256 + lane * 4;                       \
        scat(v0, g0);                                                   \
        scat(v1, g0 + 1024);                                            \
    } while (0)

        PST(0); PST(1);
        #pragma unroll
        for (int c = 0; c < 9; ++c) {
            if (c < 7) { PST(c + 2); VM(4); }
            else if (c == 7) { VM(2); }
            else { VM(0); }
            PRC(c);
        }
#undef PRC
#undef PST
    } else {
        float* Vsh = (float*)Lb;                   // 25,728 B used
        int bid2 = bid - nst;
        const int bz = bid2 % cur, u = bid2 / cur; // u in [0,72)
        int k0 = u / 3, tj = u % 3;
        int b  = b0 + bz;
        int t  = threadIdx.x;
        f32x4 vv[6];
        #pragma unroll
        for (int p = 0; p < 6; ++p) {
            int fidx = p * 256 + t;
            int dd = fidx / 48, c4 = fidx % 48;
            vv[p] = *(const f32x4*)(f2 + ((size_t)b * C_ + k0 * 32 + dd) * HW_ + tj * 192 + c4 * 4);
        }
        #pragma unroll
        for (int p = 0; p < 6; ++p) {
            int fidx = p * 256 + t;
            int dd = fidx / 48, c4 = fidx % 48;
            #pragma unroll
            for (int e = 0; e < 4; ++e) Vsh[dd * 201 + c4 * 4 + e] = vv[p][e];
        }
        __syncthreads();
        char* ob = vt + ((size_t)(bz * 3 + tj) * NCP + k0) * 12288;
        #pragma unroll
        for (int p = 0; p < 3; ++p) {
            int o = p * 256 + t;
            int x = o & 3, n = o >> 2;
            int kc = x ^ ((n >> 1) & 3);
            half8 h;
            #pragma unroll
            for (int j = 0; j < 8; ++j) h[j] = (_Float16)Vsh[(kc * 8 + j) * 201 + n];
            *(half8*)(ob + o * 16) = h;
        }
    }
}

// ---------------------------------------------------------------------------
// qk6: S = q @ kv^T. Tile 192x192, 8 waves (4Mx2N), BK=32, ring-3, depth-2
// counted-vmcnt pipeline. Epilogue: per-(row,96-col-half) partials {mx,s} +
// attnE = fp16 exp(S - mx_half). (round-18 exact)
// ---------------------------------------------------------------------------
__global__ __launch_bounds__(512, 4) void qk6(const char* __restrict__ q16,
                                              const char* __restrict__ kv16,
                                              _Float16* __restrict__ attnE,
                                              float2* __restrict__ part,
                                              int cur) {
    __shared__ __align__(16) char S[3][24576];
    const int wg = blockIdx.x;
    const int bz = wg % cur, u = wg / cur;   // u in [0,16)
    const int ti = u >> 2, tj = u & 3;
    const int t = threadIdx.x, lane = t & 63, w = t >> 6;
    const int rsub = lane >> 2, cb = (lane & 3) * 16;

    const char *p0, *p1, *p2;
    int o0, o1, o2;
    {
        auto arow = [&](int l) {
            int gr = ti * 192 + 16 * l + rsub;
            return q16 + ((size_t)(bz * 6 + (gr >> 7)) * NCQ) * 8192 + (gr & 127) * 64 + cb;
        };
        auto brow = [&](int l) {
            int gd = tj * 192 + 16 * l + rsub;
            return kv16 + ((size_t)(bz * 6 + (gd >> 7)) * NCQ) * 8192 + (gd & 127) * 64 + cb;
        };
        if (w < 4) {
            p0 = arow(2 * w);     o0 = (2 * w) * 1024;
            p1 = arow(2 * w + 1); o1 = (2 * w + 1) * 1024;
            p2 = brow(8 + w);     o2 = 12288 + (8 + w) * 1024;
        } else {
            int v = w - 4;
            p0 = brow(2 * v);     o0 = 12288 + (2 * v) * 1024;
            p1 = brow(2 * v + 1); o1 = 12288 + (2 * v + 1) * 1024;
            p2 = arow(8 + v);     o2 = (8 + v) * 1024;
        }
    }

    const int wr = (w >> 1) * 48, wc = (w & 1) * 96;
    const int r16 = lane & 15, cg = lane >> 4;
    int offA[3], offB[6];
    #pragma unroll
    for (int m = 0; m < 3; ++m) {
        int ra = wr + m * 16 + r16;
        offA[m] = ra * 64 + ((cg ^ ((ra >> 1) & 3)) << 4);
    }
    #pragma unroll
    for (int n = 0; n < 6; ++n) {
        int rb = wc + n * 16 + r16;
        offB[n] = 12288 + rb * 64 + ((cg ^ ((rb >> 1) & 3)) << 4);
    }

    f32x4 acc[3][6] = {};

#define STG(SLOT) do {                          \
        char* sb_ = &S[SLOT][0];                \
        g2l16(p0, sb_ + o0);                    \
        g2l16(p1, sb_ + o1);                    \
        g2l16(p2, sb_ + o2);                    \
        p0 += 8192; p1 += 8192; p2 += 8192;     \
    } while (0)

    STG(0); STG(1);
    int rd = 0, st = 2;
    for (int c = 0; c < NCQ; ++c) {
        if (c + 2 < NCQ) {
            STG(st); st = (st == 2) ? 0 : st + 1;
            VM(6);
        } else if (c + 2 == NCQ) {
            VM(3);
        } else {
            VM(0);
        }
        __builtin_amdgcn_s_barrier();
        const char* sb = &S[rd][0];
        rd = (rd == 2) ? 0 : rd + 1;
        half8 a0 = *(const half8*)(sb + offA[0]);
        half8 a1 = *(const half8*)(sb + offA[1]);
        half8 a2 = *(const half8*)(sb + offA[2]);
        __builtin_amdgcn_s_setprio(1);
        #pragma unroll
        for (int n = 0; n < 6; ++n) {
            half8 bn = *(const half8*)(sb + offB[n]);
            acc[0][n] = __builtin_amdgcn_mfma_f32_16x16x32_f16(a0, bn, acc[0][n], 0, 0, 0);
            acc[1][n] = __builtin_amdgcn_mfma_f32_16x16x32_f16(a1, bn, acc[1][n], 0, 0, 0);
            acc[2][n] = __builtin_amdgcn_mfma_f32_16x16x32_f16(a2, bn, acc[2][n], 0, 0, 0);
        }
        __builtin_amdgcn_s_setprio(0);
        __builtin_amdgcn_s_barrier();
    }
#undef STG

    // --- partials first (captures mx per (m,rg)) ---
    const int half = w & 1;
    float mxv[3][4];                 // static-indexed only
    #pragma unroll
    for (int m = 0; m < 3; ++m)
        #pragma unroll
        for (int rg = 0; rg < 4; ++rg) {
            float mx = -1e30f;
            #pragma unroll
            for (int n = 0; n < 6; ++n) mx = fmaxf(mx, acc[m][n][rg]);
            #pragma unroll
            for (int o = 1; o < 16; o <<= 1) mx = fmaxf(mx, __shfl_xor(mx, o));
            mxv[m][rg] = mx;
            float s = 0.f;
            #pragma unroll
            for (int n = 0; n < 6; ++n) s += __expf(acc[m][n][rg] - mx);
            #pragma unroll
            for (int o = 1; o < 16; o <<= 1) s += __shfl_xor(s, o);
            if ((lane & 15) == 0) {
                int row = wr + m * 16 + (lane >> 4) * 4 + rg;
                part[((size_t)bz * C_ + ti * 192 + row) * 8 + tj * 2 + half] =
                    make_float2(mx, s);
            }
        }

    // --- attnE write: fp16 exp(S - mx_half), linearized chunk-major ---
    const int col = lane & 15, rbase = (lane >> 4) * 4;
    #pragma unroll
    for (int m = 0; m < 3; ++m)
        #pragma unroll
        for (int n = 0; n < 6; ++n)
            #pragma unroll
            for (int rg = 0; rg < 4; ++rg) {
                int grow = ti * 192 + wr + m * 16 + rbase + rg;
                int gcol = tj * 192 + wc + n * 16 + col;
                attnE[(((size_t)bz * 6 + (grow >> 7)) * NCP + (gcol >> 5)) * 4096
                      + (grow & 127) * 32 + (gcol & 31)] =
                    (_Float16)__expf(acc[m][n][rg] - mxv[m][rg]);
            }
}

// ---------------------------------------------------------------------------
// pv11: out = (gamma*P)@V + feat1. Paired chunks (12 unrolled phases),
// ring-4 of {A 8KB | B 12KB} slots, fp16 exp A-stream with per-(row,half)
// rescale. (round-18 exact)
// ---------------------------------------------------------------------------
__global__ __launch_bounds__(512, 4) void pv11(const _Float16* __restrict__ attnE,
                                               const char* __restrict__ vt,
                                               const float2* __restrict__ part,
                                               const float* __restrict__ gamma,
                                               const float* __restrict__ f1,
                                               float* __restrict__ out,
                                               int b0, int cur) {
    __shared__ __align__(16) char S[4][20480];   // per slot: A 8KB | B 12KB
    const int wg = blockIdx.x;
    const int bz = wg % cur, u = wg / cur;       // u in [0,18)
    const int ti = u / 3, tj = u % 3;
    const int t = threadIdx.x, lane = t & 63, w = t >> 6;
    const int rsub = lane >> 2, cbb = (lane & 3) * 16;

    const int r0 = t >> 2;
    const int g4 = t & 3;
    const char* srcA = (const char*)(attnE + (((size_t)bz * 6 + ti) * NCP) * 4096) + t * 16;
    const int aw0 = r0 * 64 + ((g4 ^ ((r0 >> 1) & 3)) << 4);

    float2 pm[8];
    float m_row, inv;
    {
        const float2* pr = part + ((size_t)bz * C_ + ti * 128 + r0) * 8;
        #pragma unroll
        for (int i = 0; i < 8; ++i) pm[i] = pr[i];
        float m = pm[0].x;
        #pragma unroll
        for (int i = 1; i < 8; ++i) m = fmaxf(m, pm[i].x);
        float s = 0.f;
        #pragma unroll
        for (int i = 0; i < 8; ++i) s += pm[i].y * __expf(pm[i].x - m);
        m_row = m;
        inv = gamma[0] / s;
    }

    const char* vbase = vt + ((size_t)(bz * 3 + tj) * NCP) * 12288;
    const char *pB0, *pB1;
    int ob0, ob1;
    if (w < 4) {
        pB0 = vbase + (32 * w + rsub) * 64 + cbb;          ob0 = 8192 + (32 * w) * 64;
        pB1 = vbase + (32 * w + 16 + rsub) * 64 + cbb;     ob1 = 8192 + (32 * w + 16) * 64;
    } else {
        pB0 = vbase + (128 + 16 * (w - 4) + rsub) * 64 + cbb;
        ob0 = 8192 + (128 + 16 * (w - 4)) * 64;
        pB1 = vbase; ob1 = 0;  // unused
    }

    const int wr = (w >> 2) * 64, wc = (w & 3) * 48;
    const int r16 = lane & 15, cg = lane >> 4;
    int offA[4], offB[3];
    #pragma unroll
    for (int m = 0; m < 4; ++m) {
        int ra = wr + m * 16 + r16;
        offA[m] = ra * 64 + ((cg ^ ((ra >> 1) & 3)) << 4);
    }
    #pragma unroll
    for (int n = 0; n < 3; ++n) {
        int rb = wc + n * 16 + r16;
        offB[n] = 8192 + rb * 64 + ((cg ^ ((rb >> 1) & 3)) << 4);
    }

    f32x4 acc[4][3] = {};
    half8 vaA, vaB;

#define STG_B(SLOT) do {                                  \
        g2l16(pB0, &S[SLOT][0] + ob0); pB0 += 12288;      \
        if (w < 4) { g2l16(pB1, &S[SLOT][0] + ob1); pB1 += 12288; } \
    } while (0)
#define LD_A(V) do { V = *(const half8*)srcA; srcA += 8192; } while (0)
#define WR_A(SLOT, V, H) do {                                          \
        const float fac_ = __expf(pm[H].x - m_row) * inv;              \
        half8 h_;                                                      \
        _Pragma("unroll")                                              \
        for (int e = 0; e < 8; ++e)                                    \
            h_[e] = (_Float16)((float)V[e] * fac_);                    \
        *(half8*)(&S[SLOT][0] + aw0) = h_;                             \
    } while (0)
#define MFMA_SLOT(SB) do {                                             \
        const char* sb_ = (SB);                                        \
        half8 a_[4], b_[3];                                            \
        _Pragma("unroll")                                              \
        for (int m = 0; m < 4; ++m) a_[m] = *(const half8*)(sb_ + offA[m]); \
        _Pragma("unroll")                                              \
        for (int n = 0; n < 3; ++n) b_[n] = *(const half8*)(sb_ + offB[n]); \
        _Pragma("unroll")                                              \
        for (int m = 0; m < 4; ++m)                                    \
            _Pragma("unroll")                                          \
            for (int n = 0; n < 3; ++n)                                \
                acc[m][n] = __builtin_amdgcn_mfma_f32_16x16x32_f16(a_[m], b_[n], acc[m][n], 0, 0, 0); \
    } while (0)

    LD_A(vaA);
    WR_A(0, vaA, 0);
    LD_A(vaB);
    WR_A(1, vaB, 0);
    STG_B(0); STG_B(1);
    LD_A(vaA);               // chunk 2
    LD_A(vaB);               // chunk 3

    #pragma unroll
    for (int p = 0; p < 12; ++p) {
        const int sa = (2 * p) & 3;
        asm volatile("s_waitcnt lgkmcnt(0)" ::: "memory");
        __builtin_amdgcn_s_barrier();
        if (p < 11) { STG_B((sa + 2) & 3); STG_B((sa + 3) & 3); }
        if (p < 11) { if (w < 4) VM(6); else VM(4); }
        else        { VM(0); }
        __builtin_amdgcn_s_barrier();

        __builtin_amdgcn_s_setprio(1);
        MFMA_SLOT(&S[sa][0]);
        MFMA_SLOT(&S[sa ^ 1][0]);
        __builtin_amdgcn_s_setprio(0);

        if (p < 11) {
            WR_A((sa + 2) & 3, vaA, (2 * p + 2) / 3);
            WR_A((sa + 3) & 3, vaB, (2 * p + 3) / 3);
            if (p < 10) {
                LD_A(vaA);
                LD_A(vaB);
            }
        }
    }
#undef MFMA_SLOT
#undef WR_A
#undef LD_A
#undef STG_B

    const int b = b0 + bz;
    const float* f1b = f1 + ((size_t)b * C_ + ti * 128) * HW_ + tj * 192;
    float*       ob  = out + ((size_t)b * C_ + ti * 128) * HW_ + tj * 192;
    const int col = lane & 15, rbase = (lane >> 4) * 4;
    #pragma unroll
    for (int m = 0; m < 4; ++m)
        #pragma unroll
        for (int n = 0; n < 3; ++n)
            #pragma unroll
            for (int rg = 0; rg < 4; ++rg) {
                int r2 = wr + m * 16 + rbase + rg;
                int c2 = wc + n * 16 + col;
                ob[(size_t)r2 * HW_ + c2] = acc[m][n][rg] + f1b[(size_t)r2 * HW_ + c2];
            }
}

// ---------------------------------------------------------------------------
extern "C" void kernel_launch(void* const* d_in, const int* in_sizes, int n_in,
                              void* d_out, int out_size, void* d_ws, size_t ws_size,
                              hipStream_t stream) {
    const float* feat1 = (const float*)d_in[0];
    const float* feat2 = (const float*)d_in[1];
    const float* gamma = (const float*)d_in[2];
    float* out = (float*)d_out;

    const size_t SZ_Q    = (size_t)C_ * HW_ * 2;      //   884,736 B/batch
    const size_t SZ_ATTN = (size_t)C_ * C_  * 2;      // 1,179,648 B/batch (fp16 exp)
    const size_t SZ_PART = (size_t)C_ * 8 * 8;        //    49,152 B/batch
    const size_t per_batch = SZ_ATTN + 3 * SZ_Q + SZ_PART;

    int nb = (int)(ws_size / per_batch);
    if (nb < 1) nb = 1;
    if (nb > B_) nb = B_;

    char* ws        = (char*)d_ws;
    _Float16* attnE = (_Float16*)ws;
    char* q16       = ws + (size_t)nb * SZ_ATTN;
    char* kv16      = q16 + (size_t)nb * SZ_Q;
    char* vtb       = kv16 + (size_t)nb * SZ_Q;
    float2* part    = (float2*)(vtb + (size_t)nb * SZ_Q);

    for (int b0 = 0; b0 < B_; b0 += nb) {
        int cur = (B_ - b0 < nb) ? (B_ - b0) : nb;
        prep6<<<cur * 120, 256, 0, stream>>>(feat1, feat2, q16, kv16, vtb, b0, cur, cur * 48);
        qk6<<<cur * 16, 512, 0, stream>>>(q16, kv16, attnE, part, cur);
        pv11<<<cur * 18, 512, 0, stream>>>(attnE, vtb, part, gamma, feat1, out, b0, cur);
    }
}

// Round 22
// 122.836 us; speedup vs baseline: 1.0574x; 1.0574x over previous
//
#include <hip/hip_runtime.h>

// Problem constants: B=32, C=768, H=W=24 -> HW=576
#define B_  32
#define C_  768
#define HW_ 576

#define NCQ 18               // HW_/32 k-chunks (qk)
#define NCP 24               // C_/32 k-chunks (pv)

typedef _Float16 half8 __attribute__((ext_vector_type(8)));
typedef _Float16 half4 __attribute__((ext_vector_type(4)));
typedef float    f32x4 __attribute__((ext_vector_type(4)));

__device__ __forceinline__ void g2l16(const void* g, void* l) {
    __builtin_amdgcn_global_load_lds(
        (const __attribute__((address_space(1))) unsigned int*)g,
        (__attribute__((address_space(3))) unsigned int*)l, 16, 0, 0);
}

#define VM(N) asm volatile("s_waitcnt vmcnt(" #N ")" ::: "memory")

// attnE holds exp(S - mx_half) in fp16, LINEARIZED chunk-major:
//   elem index = ((bz*6 + strip)*24 + chunk)*4096 + row_in_strip*32 + col_in_chunk
// pv rescales by exp(mx_half - m_row)*gamma/s_row per (row, 96-col half).

// ---------------------------------------------------------------------------
// prep7: SINGLE DELTA vs round-19 prep4: f2 is read ONCE. Each f2 block
// (32-channel group) builds the kv16-image in LDS (prep4's exact sequential-
// read + coalesced-store path), then derives its vt tile FROM THE SAME LDS
// IMAGE (8x u16 gathers; x-swizzle algebra verified: vt(tj,n,x,j) =
// image[row kc*8+j, col tj*192+n], rowx = (kkc>>3)^((j>>1)&3)). f1 blocks
// = prep4 path exact. Output bytes identical -> downstream bit-identical.
// ---------------------------------------------------------------------------
__global__ __launch_bounds__(256) void prep7(const float* __restrict__ f1,
                                             const float* __restrict__ f2,
                                             char* __restrict__ q16,
                                             char* __restrict__ kv16,
                                             char* __restrict__ vt,
                                             int b0, int cur) {
    __shared__ __align__(16) char Lb[18 * 2064];   // 37,152 B (18 k0-segs + pad)
    const int bid = blockIdx.x;
    const int bz = bid % cur, u = bid / cur;       // u in [0,48)
    const int sel = (u >= 24);                     // 0: f1->q16, 1: f2->kv16+vt
    const int g   = sel ? (u - 24) : u;            // 32-row group in [0,24)
    const int ti  = g >> 2, rg = g & 3;
    const float* s = (sel ? f2 : f1) + ((size_t)(b0 + bz) * C_ + g * 32) * HW_;
    char* d = (sel ? kv16 : q16) + ((size_t)(bz * 6 + ti)) * (NCQ * 8192) + rg * 2048;
    const int t = threadIdx.x;

    // phase 1: sequential 16B/lane reads -> kv16-image LDS scatter
    // (x = (kk>>3) ^ ((row>>1)&3); within a 32-row group (row>>1)&3 ==
    // (row_l>>1)&3 since rg*16 = 0 mod 4)
    #pragma unroll
    for (int it = 0; it < 18; ++it) {
        int gg    = it * 1024 + t * 4;             // float idx in 32x576 group
        int row_l = gg / 576;
        int col   = gg - row_l * 576;
        int k0    = col >> 5, kk = col & 31;
        int x     = (kk >> 3) ^ ((row_l >> 1) & 3);
        int loff  = k0 * 2064 + row_l * 64 + x * 16 + (kk & 7) * 2;
        f32x4 v = *(const f32x4*)(s + gg);
        half4 h;
        #pragma unroll
        for (int e = 0; e < 4; ++e) h[e] = (_Float16)v[e];
        *(half4*)(Lb + loff) = h;
    }
    __syncthreads();

    // phase 2: linear LDS read -> contiguous global stores (16B/lane)
    #pragma unroll
    for (int p = 0; p < 9; ++p) {
        int idx = p * 256 + t;                     // 0..2303
        int k0  = idx >> 7;
        int wi  = idx & 127;
        *(f32x4*)(d + (size_t)k0 * 8192 + wi * 16) =
            *(const f32x4*)(Lb + k0 * 2064 + wi * 16);
    }

    // phase 3 (f2 blocks only): vt tile from the same LDS image
    if (sel) {
        #pragma unroll
        for (int p = 0; p < 9; ++p) {
            int s2 = p * 256 + t;                  // 0..2303 output half8 slots
            int tj = s2 / 768, r2 = s2 - tj * 768;
            int n  = r2 >> 2, x = r2 & 3;
            int kc = x ^ ((n >> 1) & 3);
            int col = tj * 192 + n;
            int k0c = col >> 5, kkc = col & 31;
            half8 h;
            #pragma unroll
            for (int j = 0; j < 8; ++j) {
                int row_l = kc * 8 + j;
                int rowx  = (kkc >> 3) ^ ((j >> 1) & 3);
                h[j] = *(const _Float16*)(Lb + k0c * 2064 + row_l * 64 + rowx * 16 + (kkc & 7) * 2);
            }
            *(half8*)(vt + ((size_t)(bz * 3 + tj) * NCP + g) * 12288 + n * 64 + x * 16) = h;
        }
    }
}

// ---------------------------------------------------------------------------
// qk6: S = q @ kv^T. Tile 192x192, 8 waves (4Mx2N), BK=32, ring-3, depth-2
// counted-vmcnt pipeline. Epilogue: per-(row,96-col-half) partials {mx,s} +
// attnE = fp16 exp(S - mx_half). (round-18 exact)
// ---------------------------------------------------------------------------
__global__ __launch_bounds__(512, 4) void qk6(const char* __restrict__ q16,
                                              const char* __restrict__ kv16,
                                              _Float16* __restrict__ attnE,
                                              float2* __restrict__ part,
                                              int cur) {
    __shared__ __align__(16) char S[3][24576];
    const int wg = blockIdx.x;
    const int bz = wg % cur, u = wg / cur;   // u in [0,16)
    const int ti = u >> 2, tj = u & 3;
    const int t = threadIdx.x, lane = t & 63, w = t >> 6;
    const int rsub = lane >> 2, cb = (lane & 3) * 16;

    const char *p0, *p1, *p2;
    int o0, o1, o2;
    {
        auto arow = [&](int l) {
            int gr = ti * 192 + 16 * l + rsub;
            return q16 + ((size_t)(bz * 6 + (gr >> 7)) * NCQ) * 8192 + (gr & 127) * 64 + cb;
        };
        auto brow = [&](int l) {
            int gd = tj * 192 + 16 * l + rsub;
            return kv16 + ((size_t)(bz * 6 + (gd >> 7)) * NCQ) * 8192 + (gd & 127) * 64 + cb;
        };
        if (w < 4) {
            p0 = arow(2 * w);     o0 = (2 * w) * 1024;
            p1 = arow(2 * w + 1); o1 = (2 * w + 1) * 1024;
            p2 = brow(8 + w);     o2 = 12288 + (8 + w) * 1024;
        } else {
            int v = w - 4;
            p0 = brow(2 * v);     o0 = 12288 + (2 * v) * 1024;
            p1 = brow(2 * v + 1); o1 = 12288 + (2 * v + 1) * 1024;
            p2 = arow(8 + v);     o2 = (8 + v) * 1024;
        }
    }

    const int wr = (w >> 1) * 48, wc = (w & 1) * 96;
    const int r16 = lane & 15, cg = lane >> 4;
    int offA[3], offB[6];
    #pragma unroll
    for (int m = 0; m < 3; ++m) {
        int ra = wr + m * 16 + r16;
        offA[m] = ra * 64 + ((cg ^ ((ra >> 1) & 3)) << 4);
    }
    #pragma unroll
    for (int n = 0; n < 6; ++n) {
        int rb = wc + n * 16 + r16;
        offB[n] = 12288 + rb * 64 + ((cg ^ ((rb >> 1) & 3)) << 4);
    }

    f32x4 acc[3][6] = {};

#define STG(SLOT) do {                          \
        char* sb_ = &S[SLOT][0];                \
        g2l16(p0, sb_ + o0);                    \
        g2l16(p1, sb_ + o1);                    \
        g2l16(p2, sb_ + o2);                    \
        p0 += 8192; p1 += 8192; p2 += 8192;     \
    } while (0)

    STG(0); STG(1);
    int rd = 0, st = 2;
    for (int c = 0; c < NCQ; ++c) {
        if (c + 2 < NCQ) {
            STG(st); st = (st == 2) ? 0 : st + 1;
            VM(6);
        } else if (c + 2 == NCQ) {
            VM(3);
        } else {
            VM(0);
        }
        __builtin_amdgcn_s_barrier();
        const char* sb = &S[rd][0];
        rd = (rd == 2) ? 0 : rd + 1;
        half8 a0 = *(const half8*)(sb + offA[0]);
        half8 a1 = *(const half8*)(sb + offA[1]);
        half8 a2 = *(const half8*)(sb + offA[2]);
        __builtin_amdgcn_s_setprio(1);
        #pragma unroll
        for (int n = 0; n < 6; ++n) {
            half8 bn = *(const half8*)(sb + offB[n]);
            acc[0][n] = __builtin_amdgcn_mfma_f32_16x16x32_f16(a0, bn, acc[0][n], 0, 0, 0);
            acc[1][n] = __builtin_amdgcn_mfma_f32_16x16x32_f16(a1, bn, acc[1][n], 0, 0, 0);
            acc[2][n] = __builtin_amdgcn_mfma_f32_16x16x32_f16(a2, bn, acc[2][n], 0, 0, 0);
        }
        __builtin_amdgcn_s_setprio(0);
        __builtin_amdgcn_s_barrier();
    }
#undef STG

    // --- partials first (captures mx per (m,rg)) ---
    const int half = w & 1;
    float mxv[3][4];                 // static-indexed only
    #pragma unroll
    for (int m = 0; m < 3; ++m)
        #pragma unroll
        for (int rg = 0; rg < 4; ++rg) {
            float mx = -1e30f;
            #pragma unroll
            for (int n = 0; n < 6; ++n) mx = fmaxf(mx, acc[m][n][rg]);
            #pragma unroll
            for (int o = 1; o < 16; o <<= 1) mx = fmaxf(mx, __shfl_xor(mx, o));
            mxv[m][rg] = mx;
            float s = 0.f;
            #pragma unroll
            for (int n = 0; n < 6; ++n) s += __expf(acc[m][n][rg] - mx);
            #pragma unroll
            for (int o = 1; o < 16; o <<= 1) s += __shfl_xor(s, o);
            if ((lane & 15) == 0) {
                int row = wr + m * 16 + (lane >> 4) * 4 + rg;
                part[((size_t)bz * C_ + ti * 192 + row) * 8 + tj * 2 + half] =
                    make_float2(mx, s);
            }
        }

    // --- attnE write: fp16 exp(S - mx_half), linearized chunk-major ---
    const int col = lane & 15, rbase = (lane >> 4) * 4;
    #pragma unroll
    for (int m = 0; m < 3; ++m)
        #pragma unroll
        for (int n = 0; n < 6; ++n)
            #pragma unroll
            for (int rg = 0; rg < 4; ++rg) {
                int grow = ti * 192 + wr + m * 16 + rbase + rg;
                int gcol = tj * 192 + wc + n * 16 + col;
                attnE[(((size_t)bz * 6 + (grow >> 7)) * NCP + (gcol >> 5)) * 4096
                      + (grow & 127) * 32 + (gcol & 31)] =
                    (_Float16)__expf(acc[m][n][rg] - mxv[m][rg]);
            }
}

// ---------------------------------------------------------------------------
// pv11: out = (gamma*P)@V + feat1. Paired chunks (12 unrolled phases),
// ring-4 of {A 8KB | B 12KB} slots, fp16 exp A-stream with per-(row,half)
// rescale. (round-18 exact)
// ---------------------------------------------------------------------------
__global__ __launch_bounds__(512, 4) void pv11(const _Float16* __restrict__ attnE,
                                               const char* __restrict__ vt,
                                               const float2* __restrict__ part,
                                               const float* __restrict__ gamma,
                                               const float* __restrict__ f1,
                                               float* __restrict__ out,
                                               int b0, int cur) {
    __shared__ __align__(16) char S[4][20480];   // per slot: A 8KB | B 12KB
    const int wg = blockIdx.x;
    const int bz = wg % cur, u = wg / cur;       // u in [0,18)
    const int ti = u / 3, tj = u % 3;
    const int t = threadIdx.x, lane = t & 63, w = t >> 6;
    const int rsub = lane >> 2, cbb = (lane & 3) * 16;

    const int r0 = t >> 2;
    const int g4 = t & 3;
    const char* srcA = (const char*)(attnE + (((size_t)bz * 6 + ti) * NCP) * 4096) + t * 16;
    const int aw0 = r0 * 64 + ((g4 ^ ((r0 >> 1) & 3)) << 4);

    float2 pm[8];
    float m_row, inv;
    {
        const float2* pr = part + ((size_t)bz * C_ + ti * 128 + r0) * 8;
        #pragma unroll
        for (int i = 0; i < 8; ++i) pm[i] = pr[i];
        float m = pm[0].x;
        #pragma unroll
        for (int i = 1; i < 8; ++i) m = fmaxf(m, pm[i].x);
        float s = 0.f;
        #pragma unroll
        for (int i = 0; i < 8; ++i) s += pm[i].y * __expf(pm[i].x - m);
        m_row = m;
        inv = gamma[0] / s;
    }

    const char* vbase = vt + ((size_t)(bz * 3 + tj) * NCP) * 12288;
    const char *pB0, *pB1;
    int ob0, ob1;
    if (w < 4) {
        pB0 = vbase + (32 * w + rsub) * 64 + cbb;          ob0 = 8192 + (32 * w) * 64;
        pB1 = vbase + (32 * w + 16 + rsub) * 64 + cbb;     ob1 = 8192 + (32 * w + 16) * 64;
    } else {
        pB0 = vbase + (128 + 16 * (w - 4) + rsub) * 64 + cbb;
        ob0 = 8192 + (128 + 16 * (w - 4)) * 64;
        pB1 = vbase; ob1 = 0;  // unused
    }

    const int wr = (w >> 2) * 64, wc = (w & 3) * 48;
    const int r16 = lane & 15, cg = lane >> 4;
    int offA[4], offB[3];
    #pragma unroll
    for (int m = 0; m < 4; ++m) {
        int ra = wr + m * 16 + r16;
        offA[m] = ra * 64 + ((cg ^ ((ra >> 1) & 3)) << 4);
    }
    #pragma unroll
    for (int n = 0; n < 3; ++n) {
        int rb = wc + n * 16 + r16;
        offB[n] = 8192 + rb * 64 + ((cg ^ ((rb >> 1) & 3)) << 4);
    }

    f32x4 acc[4][3] = {};
    half8 vaA, vaB;

#define STG_B(SLOT) do {                                  \
        g2l16(pB0, &S[SLOT][0] + ob0); pB0 += 12288;      \
        if (w < 4) { g2l16(pB1, &S[SLOT][0] + ob1); pB1 += 12288; } \
    } while (0)
#define LD_A(V) do { V = *(const half8*)srcA; srcA += 8192; } while (0)
#define WR_A(SLOT, V, H) do {                                          \
        const float fac_ = __expf(pm[H].x - m_row) * inv;              \
        half8 h_;                                                      \
        _Pragma("unroll")                                              \
        for (int e = 0; e < 8; ++e)                                    \
            h_[e] = (_Float16)((float)V[e] * fac_);                    \
        *(half8*)(&S[SLOT][0] + aw0) = h_;                             \
    } while (0)
#define MFMA_SLOT(SB) do {                                             \
        const char* sb_ = (SB);                                        \
        half8 a_[4], b_[3];                                            \
        _Pragma("unroll")                                              \
        for (int m = 0; m < 4; ++m) a_[m] = *(const half8*)(sb_ + offA[m]); \
        _Pragma("unroll")                                              \
        for (int n = 0; n < 3; ++n) b_[n] = *(const half8*)(sb_ + offB[n]); \
        _Pragma("unroll")                                              \
        for (int m = 0; m < 4; ++m)                                    \
            _Pragma("unroll")                                          \
            for (int n = 0; n < 3; ++n)                                \
                acc[m][n] = __builtin_amdgcn_mfma_f32_16x16x32_f16(a_[m], b_[n], acc[m][n], 0, 0, 0); \
    } while (0)

    LD_A(vaA);
    WR_A(0, vaA, 0);
    LD_A(vaB);
    WR_A(1, vaB, 0);
    STG_B(0); STG_B(1);
    LD_A(vaA);               // chunk 2
    LD_A(vaB);               // chunk 3

    #pragma unroll
    for (int p = 0; p < 12; ++p) {
        const int sa = (2 * p) & 3;
        asm volatile("s_waitcnt lgkmcnt(0)" ::: "memory");
        __builtin_amdgcn_s_barrier();
        if (p < 11) { STG_B((sa + 2) & 3); STG_B((sa + 3) & 3); }
        if (p < 11) { if (w < 4) VM(6); else VM(4); }
        else        { VM(0); }
        __builtin_amdgcn_s_barrier();

        __builtin_amdgcn_s_setprio(1);
        MFMA_SLOT(&S[sa][0]);
        MFMA_SLOT(&S[sa ^ 1][0]);
        __builtin_amdgcn_s_setprio(0);

        if (p < 11) {
            WR_A((sa + 2) & 3, vaA, (2 * p + 2) / 3);
            WR_A((sa + 3) & 3, vaB, (2 * p + 3) / 3);
            if (p < 10) {
                LD_A(vaA);
                LD_A(vaB);
            }
        }
    }
#undef MFMA_SLOT
#undef WR_A
#undef LD_A
#undef STG_B

    const int b = b0 + bz;
    const float* f1b = f1 + ((size_t)b * C_ + ti * 128) * HW_ + tj * 192;
    float*       ob  = out + ((size_t)b * C_ + ti * 128) * HW_ + tj * 192;
    const int col = lane & 15, rbase = (lane >> 4) * 4;
    #pragma unroll
    for (int m = 0; m < 4; ++m)
        #pragma unroll
        for (int n = 0; n < 3; ++n)
            #pragma unroll
            for (int rg = 0; rg < 4; ++rg) {
                int r2 = wr + m * 16 + rbase + rg;
                int c2 = wc + n * 16 + col;
                ob[(size_t)r2 * HW_ + c2] = acc[m][n][rg] + f1b[(size_t)r2 * HW_ + c2];
            }
}

// ---------------------------------------------------------------------------
extern "C" void kernel_launch(void* const* d_in, const int* in_sizes, int n_in,
                              void* d_out, int out_size, void* d_ws, size_t ws_size,
                              hipStream_t stream) {
    const float* feat1 = (const float*)d_in[0];
    const float* feat2 = (const float*)d_in[1];
    const float* gamma = (const float*)d_in[2];
    float* out = (float*)d_out;

    const size_t SZ_Q    = (size_t)C_ * HW_ * 2;      //   884,736 B/batch
    const size_t SZ_ATTN = (size_t)C_ * C_  * 2;      // 1,179,648 B/batch (fp16 exp)
    const size_t SZ_PART = (size_t)C_ * 8 * 8;        //    49,152 B/batch
    const size_t per_batch = SZ_ATTN + 3 * SZ_Q + SZ_PART;

    int nb = (int)(ws_size / per_batch);
    if (nb < 1) nb = 1;
    if (nb > B_) nb = B_;

    char* ws        = (char*)d_ws;
    _Float16* attnE = (_Float16*)ws;
    char* q16       = ws + (size_t)nb * SZ_ATTN;
    char* kv16      = q16 + (size_t)nb * SZ_Q;
    char* vtb       = kv16 + (size_t)nb * SZ_Q;
    float2* part    = (float2*)(vtb + (size_t)nb * SZ_Q);

    for (int b0 = 0; b0 < B_; b0 += nb) {
        int cur = (B_ - b0 < nb) ? (B_ - b0) : nb;
        prep7<<<cur * 48, 256, 0, stream>>>(feat1, feat2, q16, kv16, vtb, b0, cur);
        qk6<<<cur * 16, 512, 0, stream>>>(q16, kv16, attnE, part, cur);
        pv11<<<cur * 18, 512, 0, stream>>>(attnE, vtb, part, gamma, feat1, out, b0, cur);
    }
}